// Round 5
// baseline (1204.128 us; speedup 1.0000x reference)
//
#include <hip/hip_runtime.h>

// SpatialGrid4D: quadrilinear interpolation of a (32,32,32,32,8) f32 grid at
// N=4194304 points. Grid strides (floats): L=1, U=8, V=256, W=8192, Q=262144.
// Weights: a<->U, b<->V, g<->W, d<->Q (per reference lerp order).

typedef float v4f __attribute__((ext_vector_type(4)));

#define BLOCK 256

__global__ __launch_bounds__(BLOCK) void sg4d_kernel(
    const v4f*  __restrict__ uvwq,   // N x 4
    const float* __restrict__ grid,  // 32^4 x 8
    v4f*        __restrict__ out,    // N x 8 (as 2x v4f)
    int n)
{
    int i = blockIdx.x * BLOCK + threadIdx.x;
    if (i >= n) return;

    v4f p = __builtin_nontemporal_load(&uvwq[i]);  // u, v, w, q

    float fu = p.x * 31.0f;
    float fv = p.y * 31.0f;
    float fw = p.z * 31.0f;
    float fq = p.w * 31.0f;
    int iu = (int)fu, iv = (int)fv, iw = (int)fw, iq = (int)fq;
    float a = fu - (float)iu;   // U weight
    float b = fv - (float)iv;   // V weight
    float g = fw - (float)iw;   // W weight
    float d = fq - (float)iq;   // Q weight

    const float* base = grid + ((((iq * 32 + iw) * 32) + iv) * 32 + iu) * 8;

    // 8 chunks (oq, ow, ov), each 16 contiguous floats = corners ou=0 and ou=1.
    // Immediately lerp over a to keep live registers at 8 floats per chunk.
    float xa[8][8];
#pragma unroll
    for (int k = 0; k < 8; ++k) {
        const int oq = k >> 2, ow = (k >> 1) & 1, ov = k & 1;
        const v4f* c = (const v4f*)(base + oq * 262144 + ow * 8192 + ov * 256);
        v4f c0 = c[0];  // ou=0, latent 0..3
        v4f c1 = c[1];  // ou=0, latent 4..7
        v4f c2 = c[2];  // ou=1, latent 0..3
        v4f c3 = c[3];  // ou=1, latent 4..7
        xa[k][0] = fmaf(a, c2.x - c0.x, c0.x);
        xa[k][1] = fmaf(a, c2.y - c0.y, c0.y);
        xa[k][2] = fmaf(a, c2.z - c0.z, c0.z);
        xa[k][3] = fmaf(a, c2.w - c0.w, c0.w);
        xa[k][4] = fmaf(a, c3.x - c1.x, c1.x);
        xa[k][5] = fmaf(a, c3.y - c1.y, c1.y);
        xa[k][6] = fmaf(a, c3.z - c1.z, c1.z);
        xa[k][7] = fmaf(a, c3.w - c1.w, c1.w);
    }

    // Lerp over V (b): pairs (ov=0, ov=1)
    float xb[4][8];
#pragma unroll
    for (int k = 0; k < 4; ++k)
#pragma unroll
        for (int j = 0; j < 8; ++j)
            xb[k][j] = fmaf(b, xa[2 * k + 1][j] - xa[2 * k][j], xa[2 * k][j]);

    // Lerp over W (g): pairs (ow=0, ow=1)
    float xg[2][8];
#pragma unroll
    for (int k = 0; k < 2; ++k)
#pragma unroll
        for (int j = 0; j < 8; ++j)
            xg[k][j] = fmaf(g, xb[2 * k + 1][j] - xb[2 * k][j], xb[2 * k][j]);

    // Lerp over Q (d)
    float r[8];
#pragma unroll
    for (int j = 0; j < 8; ++j)
        r[j] = fmaf(d, xg[1][j] - xg[0][j], xg[0][j]);

    v4f o0 = { r[0], r[1], r[2], r[3] };
    v4f o1 = { r[4], r[5], r[6], r[7] };
    __builtin_nontemporal_store(o0, &out[2 * i + 0]);
    __builtin_nontemporal_store(o1, &out[2 * i + 1]);
}

extern "C" void kernel_launch(void* const* d_in, const int* in_sizes, int n_in,
                              void* d_out, int out_size, void* d_ws, size_t ws_size,
                              hipStream_t stream) {
    const v4f*   uvwq = (const v4f*)d_in[0];
    const float* grid = (const float*)d_in[1];
    v4f*         out  = (v4f*)d_out;
    int n = in_sizes[0] / 4;   // 4 coords per point
    int blocks = (n + BLOCK - 1) / BLOCK;
    sg4d_kernel<<<blocks, BLOCK, 0, stream>>>(uvwq, grid, out, n);
}

// Round 6
// 1017.271 us; speedup vs baseline: 1.1837x; 1.1837x over previous
//
#include <hip/hip_runtime.h>

// SpatialGrid4D: quadrilinear interp of a (32,32,32,32,8) f32 grid at N=4.19M
// uniform-random points. Round-5 profile: FETCH_SIZE=3.78GB, VALUBusy=2% →
// L2-miss-bound on random 64B gathers. Fix: counting-sort points by 20-bit
// cell key (grid memory order), then interp in sorted order with XCD-chunked
// swizzle so each XCD's L2 holds only its q-slab of the grid.

typedef float v4f __attribute__((ext_vector_type(4)));

#define NKEY (1 << 20)   // 32^4 cell keys (only 31^4 occupied)

__device__ __forceinline__ int cell_key(v4f p) {
    int iu = (int)(p.x * 31.0f);
    int iv = (int)(p.y * 31.0f);
    int iw = (int)(p.z * 31.0f);
    int iq = (int)(p.w * 31.0f);
    return (((((iq << 5) | iw) << 5) | iv) << 5) | iu;   // == linear cell order
}

__global__ __launch_bounds__(256) void k_zero(int* __restrict__ hist) {
    int i = blockIdx.x * 256 + threadIdx.x;
    if (i < NKEY) hist[i] = 0;
}

__global__ __launch_bounds__(256) void k_hist(const v4f* __restrict__ uvwq,
                                              int* __restrict__ hist, int n) {
    int stride = gridDim.x * 256;
    for (int i = blockIdx.x * 256 + threadIdx.x; i < n; i += stride)
        atomicAdd(&hist[cell_key(uvwq[i])], 1);
}

// Exclusive scan of 1M = 1024 blocks x 1024 elems (Hillis-Steele in LDS).
__global__ __launch_bounds__(1024) void k_scan_local(const int* __restrict__ hist,
                                                     int* __restrict__ cursor,
                                                     int* __restrict__ bsum) {
    __shared__ int sh[1024];
    int t = threadIdx.x, base = blockIdx.x * 1024;
    int v = hist[base + t];
    sh[t] = v;
    __syncthreads();
    for (int off = 1; off < 1024; off <<= 1) {
        int x = (t >= off) ? sh[t - off] : 0;
        __syncthreads();
        sh[t] += x;
        __syncthreads();
    }
    cursor[base + t] = sh[t] - v;          // exclusive
    if (t == 1023) bsum[blockIdx.x] = sh[t];
}

__global__ __launch_bounds__(1024) void k_scan_top(int* __restrict__ bsum) {
    __shared__ int sh[1024];
    int t = threadIdx.x;
    int v = bsum[t];
    sh[t] = v;
    __syncthreads();
    for (int off = 1; off < 1024; off <<= 1) {
        int x = (t >= off) ? sh[t - off] : 0;
        __syncthreads();
        sh[t] += x;
        __syncthreads();
    }
    bsum[t] = sh[t] - v;                   // exclusive block offsets
}

__global__ __launch_bounds__(256) void k_scan_add(int* __restrict__ cursor,
                                                  const int* __restrict__ bsum) {
    int i = blockIdx.x * 256 + threadIdx.x;
    if (i < NKEY) cursor[i] += bsum[i >> 10];
}

__global__ __launch_bounds__(256) void k_scatter(const v4f* __restrict__ uvwq,
                                                 int* __restrict__ cursor,
                                                 v4f* __restrict__ s_uvwq,
                                                 int* __restrict__ s_idx, int n) {
    int stride = gridDim.x * 256;
    for (int i = blockIdx.x * 256 + threadIdx.x; i < n; i += stride) {
        v4f p = uvwq[i];
        int pos = atomicAdd(&cursor[cell_key(p)], 1);
        s_uvwq[pos] = p;
        s_idx[pos] = i;
    }
}

// Interp over sorted points. Blocks XCD-chunk-swizzled: XCD x gets the x-th
// contiguous 1/8 of sorted order = a q-slab of the grid (~5MB, L2-resident).
__global__ __launch_bounds__(256) void k_interp(const v4f* __restrict__ s_uvwq,
                                                const int* __restrict__ s_idx,
                                                const float* __restrict__ grid,
                                                v4f* __restrict__ out, int n) {
    int nb = gridDim.x;                          // multiple of 8
    int bid = blockIdx.x;
    int swz = (bid & 7) * (nb >> 3) + (bid >> 3);
    int per = (n + nb - 1) / nb;
    int base = swz * per;
    int hi = min(n, base + per);

    for (int g = base + threadIdx.x; g < hi; g += 256) {
        v4f p = s_uvwq[g];

        float fu = p.x * 31.0f, fv = p.y * 31.0f, fw = p.z * 31.0f, fq = p.w * 31.0f;
        int iu = (int)fu, iv = (int)fv, iw = (int)fw, iq = (int)fq;
        float a = fu - (float)iu;   // U
        float b = fv - (float)iv;   // V
        float gg = fw - (float)iw;  // W
        float d = fq - (float)iq;   // Q

        const float* cellbase = grid + ((((iq * 32 + iw) * 32) + iv) * 32 + iu) * 8;

        float xa[8][8];
#pragma unroll
        for (int k = 0; k < 8; ++k) {
            const int oq = k >> 2, ow = (k >> 1) & 1, ov = k & 1;
            const v4f* c = (const v4f*)(cellbase + oq * 262144 + ow * 8192 + ov * 256);
            v4f c0 = c[0], c1 = c[1], c2 = c[2], c3 = c[3];
            xa[k][0] = fmaf(a, c2.x - c0.x, c0.x);
            xa[k][1] = fmaf(a, c2.y - c0.y, c0.y);
            xa[k][2] = fmaf(a, c2.z - c0.z, c0.z);
            xa[k][3] = fmaf(a, c2.w - c0.w, c0.w);
            xa[k][4] = fmaf(a, c3.x - c1.x, c1.x);
            xa[k][5] = fmaf(a, c3.y - c1.y, c1.y);
            xa[k][6] = fmaf(a, c3.z - c1.z, c1.z);
            xa[k][7] = fmaf(a, c3.w - c1.w, c1.w);
        }

        float xb[4][8];
#pragma unroll
        for (int k = 0; k < 4; ++k)
#pragma unroll
            for (int j = 0; j < 8; ++j)
                xb[k][j] = fmaf(b, xa[2 * k + 1][j] - xa[2 * k][j], xa[2 * k][j]);

        float xg[2][8];
#pragma unroll
        for (int k = 0; k < 2; ++k)
#pragma unroll
            for (int j = 0; j < 8; ++j)
                xg[k][j] = fmaf(gg, xb[2 * k + 1][j] - xb[2 * k][j], xb[2 * k][j]);

        float r[8];
#pragma unroll
        for (int j = 0; j < 8; ++j)
            r[j] = fmaf(d, xg[1][j] - xg[0][j], xg[0][j]);

        v4f o0 = { r[0], r[1], r[2], r[3] };
        v4f o1 = { r[4], r[5], r[6], r[7] };
        int oi = s_idx[g];
        __builtin_nontemporal_store(o0, &out[2 * oi + 0]);
        __builtin_nontemporal_store(o1, &out[2 * oi + 1]);
    }
}

// ---------------- fallback: direct (round-5 kernel) ----------------
__global__ __launch_bounds__(256) void sg4d_direct(const v4f* __restrict__ uvwq,
                                                   const float* __restrict__ grid,
                                                   v4f* __restrict__ out, int n) {
    int i = blockIdx.x * 256 + threadIdx.x;
    if (i >= n) return;
    v4f p = uvwq[i];
    float fu = p.x * 31.0f, fv = p.y * 31.0f, fw = p.z * 31.0f, fq = p.w * 31.0f;
    int iu = (int)fu, iv = (int)fv, iw = (int)fw, iq = (int)fq;
    float a = fu - (float)iu, b = fv - (float)iv, g = fw - (float)iw, d = fq - (float)iq;
    const float* base = grid + ((((iq * 32 + iw) * 32) + iv) * 32 + iu) * 8;
    float xa[8][8];
#pragma unroll
    for (int k = 0; k < 8; ++k) {
        const int oq = k >> 2, ow = (k >> 1) & 1, ov = k & 1;
        const v4f* c = (const v4f*)(base + oq * 262144 + ow * 8192 + ov * 256);
        v4f c0 = c[0], c1 = c[1], c2 = c[2], c3 = c[3];
        xa[k][0] = fmaf(a, c2.x - c0.x, c0.x);
        xa[k][1] = fmaf(a, c2.y - c0.y, c0.y);
        xa[k][2] = fmaf(a, c2.z - c0.z, c0.z);
        xa[k][3] = fmaf(a, c2.w - c0.w, c0.w);
        xa[k][4] = fmaf(a, c3.x - c1.x, c1.x);
        xa[k][5] = fmaf(a, c3.y - c1.y, c1.y);
        xa[k][6] = fmaf(a, c3.z - c1.z, c1.z);
        xa[k][7] = fmaf(a, c3.w - c1.w, c1.w);
    }
    float xb[4][8];
#pragma unroll
    for (int k = 0; k < 4; ++k)
#pragma unroll
        for (int j = 0; j < 8; ++j)
            xb[k][j] = fmaf(b, xa[2 * k + 1][j] - xa[2 * k][j], xa[2 * k][j]);
    float xg[2][8];
#pragma unroll
    for (int k = 0; k < 2; ++k)
#pragma unroll
        for (int j = 0; j < 8; ++j)
            xg[k][j] = fmaf(g, xb[2 * k + 1][j] - xb[2 * k][j], xb[2 * k][j]);
    float r[8];
#pragma unroll
    for (int j = 0; j < 8; ++j)
        r[j] = fmaf(d, xg[1][j] - xg[0][j], xg[0][j]);
    v4f o0 = { r[0], r[1], r[2], r[3] };
    v4f o1 = { r[4], r[5], r[6], r[7] };
    __builtin_nontemporal_store(o0, &out[2 * i + 0]);
    __builtin_nontemporal_store(o1, &out[2 * i + 1]);
}

extern "C" void kernel_launch(void* const* d_in, const int* in_sizes, int n_in,
                              void* d_out, int out_size, void* d_ws, size_t ws_size,
                              hipStream_t stream) {
    const v4f*   uvwq = (const v4f*)d_in[0];
    const float* grid = (const float*)d_in[1];
    v4f*         out  = (v4f*)d_out;
    int n = in_sizes[0] / 4;

    size_t need = (size_t)n * 20 + (size_t)NKEY * 8 + 4096;
    if (ws_size < need) {
        sg4d_direct<<<(n + 255) / 256, 256, 0, stream>>>(uvwq, grid, out, n);
        return;
    }

    char* w = (char*)d_ws;
    v4f* s_uvwq = (v4f*)w;
    int* s_idx  = (int*)(w + (size_t)n * 16);
    int* hist   = (int*)(w + (size_t)n * 20);
    int* cursor = hist + NKEY;
    int* bsum   = cursor + NKEY;

    k_zero      <<<NKEY / 256, 256, 0, stream>>>(hist);
    k_hist      <<<2048, 256, 0, stream>>>(uvwq, hist, n);
    k_scan_local<<<1024, 1024, 0, stream>>>(hist, cursor, bsum);
    k_scan_top  <<<1, 1024, 0, stream>>>(bsum);
    k_scan_add  <<<NKEY / 256, 256, 0, stream>>>(cursor, bsum);
    k_scatter   <<<2048, 256, 0, stream>>>(uvwq, cursor, s_uvwq, s_idx, n);
    k_interp    <<<2048, 256, 0, stream>>>(s_uvwq, s_idx, grid, out, n);
}

// Round 7
// 650.975 us; speedup vs baseline: 1.8497x; 1.5627x over previous
//
#include <hip/hip_runtime.h>

// SpatialGrid4D: quadrilinear interp of (32,32,32,32,8) f32 grid at N=4.19M
// random points. Round-6 post-mortem: scatter write-amp 4.7x (397MB), interp
// latency-bound (VALUBusy 6%, occ 29%), 1M-bucket hist/scan ~300us.
// Round 7: 256-bucket key (iq,iw>>2) -> LDS-staged partition (burst writes),
// trivial hist/scan, interp with full 8-chunk register staging for MLP.

typedef float v4f __attribute__((ext_vector_type(4)));

#define NB   256    // buckets: key = (iq<<3) | (iw>>2); bucket span ~320KB of grid
#define PBLK 2048   // points per partition block
#define PT   256    // threads per partition block

__device__ __forceinline__ int bucket_of(v4f p) {
    int iw = (int)(p.z * 31.0f);
    int iq = (int)(p.w * 31.0f);
    return (iq << 3) | (iw >> 2);
}

__global__ __launch_bounds__(PT) void k_hist(const v4f* __restrict__ uvwq,
                                             int* __restrict__ hist, int n) {
    __shared__ int lh[NB];
    int t = threadIdx.x;
    lh[t] = 0;
    __syncthreads();
    int base = blockIdx.x * PBLK;
#pragma unroll
    for (int j = 0; j < 8; ++j) {
        int i = base + j * PT + t;
        if (i < n) atomicAdd(&lh[bucket_of(uvwq[i])], 1);
    }
    __syncthreads();
    atomicAdd(&hist[t], lh[t]);
}

__global__ __launch_bounds__(NB) void k_scan(const int* __restrict__ hist,
                                             int* __restrict__ cursor) {
    __shared__ int sh[NB];
    int t = threadIdx.x;
    int v = hist[t];
    sh[t] = v;
    __syncthreads();
    for (int off = 1; off < NB; off <<= 1) {
        int x = (t >= off) ? sh[t - off] : 0;
        __syncthreads();
        sh[t] += x;
        __syncthreads();
    }
    cursor[t] = sh[t] - v;   // exclusive
}

// Partition: block loads 2048 points, bins into LDS by bucket, reserves
// contiguous global space per bucket (1 atomic/bucket/block), writes bursts.
__global__ __launch_bounds__(PT) void k_part(const v4f* __restrict__ uvwq,
                                             int* __restrict__ cursor,
                                             v4f* __restrict__ s_uvwq,
                                             int* __restrict__ s_idx, int n) {
    __shared__ int lh[NB], lbase[NB], lrsv[NB], lcnt[NB];
    __shared__ v4f sv[PBLK];
    __shared__ int si[PBLK];
    int t = threadIdx.x;
    int base = blockIdx.x * PBLK;

    lh[t] = 0;
    lcnt[t] = 0;
    __syncthreads();

    v4f p[8];
    int key[8];
#pragma unroll
    for (int j = 0; j < 8; ++j) {
        int i = base + j * PT + t;
        if (i < n) {
            p[j] = uvwq[i];
            key[j] = bucket_of(p[j]);
            atomicAdd(&lh[key[j]], 1);
        } else key[j] = -1;
    }
    __syncthreads();

    // exclusive scan of lh into lbase
    int v = lh[t];
    lbase[t] = v;
    __syncthreads();
    for (int off = 1; off < NB; off <<= 1) {
        int x = (t >= off) ? lbase[t - off] : 0;
        __syncthreads();
        lbase[t] += x;
        __syncthreads();
    }
    int excl = lbase[t] - v;
    __syncthreads();
    lbase[t] = excl;
    // reserve global range for this block's buckets
    lrsv[t] = atomicAdd(&cursor[t], v);
    __syncthreads();

    // LDS reorder (bucket-grouped within block)
#pragma unroll
    for (int j = 0; j < 8; ++j) {
        if (key[j] >= 0) {
            int r = lbase[key[j]] + atomicAdd(&lcnt[key[j]], 1);
            sv[r] = p[j];
            si[r] = base + j * PT + t;
        }
    }
    __syncthreads();

    // burst write: consecutive LDS slots -> consecutive global addrs per bucket
    int cnt = min(PBLK, n - base);
#pragma unroll
    for (int j = 0; j < 8; ++j) {
        int s = j * PT + t;
        if (s < cnt) {
            v4f q = sv[s];
            int k = bucket_of(q);
            int gp = lrsv[k] + (s - lbase[k]);
            s_uvwq[gp] = q;
            s_idx[gp] = si[s];
        }
    }
}

// Interp: 1 point/thread over sorted order; XCD-chunked swizzle keeps each
// XCD's gathers within a ~2-4MB grid window (L2-resident). All 32 corner
// loads issued before the lerp tree (full register staging -> MLP).
__global__ __launch_bounds__(256) void k_interp(const v4f* __restrict__ s_uvwq,
                                                const int* __restrict__ s_idx,
                                                const float* __restrict__ grid,
                                                v4f* __restrict__ out, int n) {
    int nb = gridDim.x;
    int b = blockIdx.x;
    int swz = (nb & 7) ? b : (b & 7) * (nb >> 3) + (b >> 3);
    int g = swz * 256 + threadIdx.x;
    if (g >= n) return;

    int oi = s_idx[g];
    v4f p = s_uvwq[g];

    float fu = p.x * 31.0f, fv = p.y * 31.0f, fw = p.z * 31.0f, fq = p.w * 31.0f;
    int iu = (int)fu, iv = (int)fv, iw = (int)fw, iq = (int)fq;
    float a = fu - (float)iu;   // U
    float bb = fv - (float)iv;  // V
    float gg = fw - (float)iw;  // W
    float d = fq - (float)iq;   // Q

    const float* cellbase = grid + ((((iq * 32 + iw) * 32) + iv) * 32 + iu) * 8;

    v4f c[8][4];
#pragma unroll
    for (int k = 0; k < 8; ++k) {
        const int oq = k >> 2, ow = (k >> 1) & 1, ov = k & 1;
        const v4f* cp = (const v4f*)(cellbase + oq * 262144 + ow * 8192 + ov * 256);
        c[k][0] = cp[0];
        c[k][1] = cp[1];
        c[k][2] = cp[2];
        c[k][3] = cp[3];
    }

    float xa[8][8];
#pragma unroll
    for (int k = 0; k < 8; ++k) {
        xa[k][0] = fmaf(a, c[k][2].x - c[k][0].x, c[k][0].x);
        xa[k][1] = fmaf(a, c[k][2].y - c[k][0].y, c[k][0].y);
        xa[k][2] = fmaf(a, c[k][2].z - c[k][0].z, c[k][0].z);
        xa[k][3] = fmaf(a, c[k][2].w - c[k][0].w, c[k][0].w);
        xa[k][4] = fmaf(a, c[k][3].x - c[k][1].x, c[k][1].x);
        xa[k][5] = fmaf(a, c[k][3].y - c[k][1].y, c[k][1].y);
        xa[k][6] = fmaf(a, c[k][3].z - c[k][1].z, c[k][1].z);
        xa[k][7] = fmaf(a, c[k][3].w - c[k][1].w, c[k][1].w);
    }

    float xb[4][8];
#pragma unroll
    for (int k = 0; k < 4; ++k)
#pragma unroll
        for (int j = 0; j < 8; ++j)
            xb[k][j] = fmaf(bb, xa[2 * k + 1][j] - xa[2 * k][j], xa[2 * k][j]);

    float xg[2][8];
#pragma unroll
    for (int k = 0; k < 2; ++k)
#pragma unroll
        for (int j = 0; j < 8; ++j)
            xg[k][j] = fmaf(gg, xb[2 * k + 1][j] - xb[2 * k][j], xb[2 * k][j]);

    float r[8];
#pragma unroll
    for (int j = 0; j < 8; ++j)
        r[j] = fmaf(d, xg[1][j] - xg[0][j], xg[0][j]);

    v4f o0 = { r[0], r[1], r[2], r[3] };
    v4f o1 = { r[4], r[5], r[6], r[7] };
    __builtin_nontemporal_store(o0, &out[2 * oi + 0]);
    __builtin_nontemporal_store(o1, &out[2 * oi + 1]);
}

// ---------------- fallback: direct ----------------
__global__ __launch_bounds__(256) void sg4d_direct(const v4f* __restrict__ uvwq,
                                                   const float* __restrict__ grid,
                                                   v4f* __restrict__ out, int n) {
    int i = blockIdx.x * 256 + threadIdx.x;
    if (i >= n) return;
    v4f p = uvwq[i];
    float fu = p.x * 31.0f, fv = p.y * 31.0f, fw = p.z * 31.0f, fq = p.w * 31.0f;
    int iu = (int)fu, iv = (int)fv, iw = (int)fw, iq = (int)fq;
    float a = fu - (float)iu, b = fv - (float)iv, g = fw - (float)iw, d = fq - (float)iq;
    const float* base = grid + ((((iq * 32 + iw) * 32) + iv) * 32 + iu) * 8;
    float xa[8][8];
#pragma unroll
    for (int k = 0; k < 8; ++k) {
        const int oq = k >> 2, ow = (k >> 1) & 1, ov = k & 1;
        const v4f* c = (const v4f*)(base + oq * 262144 + ow * 8192 + ov * 256);
        v4f c0 = c[0], c1 = c[1], c2 = c[2], c3 = c[3];
        xa[k][0] = fmaf(a, c2.x - c0.x, c0.x);
        xa[k][1] = fmaf(a, c2.y - c0.y, c0.y);
        xa[k][2] = fmaf(a, c2.z - c0.z, c0.z);
        xa[k][3] = fmaf(a, c2.w - c0.w, c0.w);
        xa[k][4] = fmaf(a, c3.x - c1.x, c1.x);
        xa[k][5] = fmaf(a, c3.y - c1.y, c1.y);
        xa[k][6] = fmaf(a, c3.z - c1.z, c1.z);
        xa[k][7] = fmaf(a, c3.w - c1.w, c1.w);
    }
    float xb[4][8];
#pragma unroll
    for (int k = 0; k < 4; ++k)
#pragma unroll
        for (int j = 0; j < 8; ++j)
            xb[k][j] = fmaf(b, xa[2 * k + 1][j] - xa[2 * k][j], xa[2 * k][j]);
    float xg[2][8];
#pragma unroll
    for (int k = 0; k < 2; ++k)
#pragma unroll
        for (int j = 0; j < 8; ++j)
            xg[k][j] = fmaf(g, xb[2 * k + 1][j] - xb[2 * k][j], xb[2 * k][j]);
    float r[8];
#pragma unroll
    for (int j = 0; j < 8; ++j)
        r[j] = fmaf(d, xg[1][j] - xg[0][j], xg[0][j]);
    v4f o0 = { r[0], r[1], r[2], r[3] };
    v4f o1 = { r[4], r[5], r[6], r[7] };
    __builtin_nontemporal_store(o0, &out[2 * i + 0]);
    __builtin_nontemporal_store(o1, &out[2 * i + 1]);
}

extern "C" void kernel_launch(void* const* d_in, const int* in_sizes, int n_in,
                              void* d_out, int out_size, void* d_ws, size_t ws_size,
                              hipStream_t stream) {
    const v4f*   uvwq = (const v4f*)d_in[0];
    const float* grid = (const float*)d_in[1];
    v4f*         out  = (v4f*)d_out;
    int n = in_sizes[0] / 4;

    size_t need = (size_t)n * 20 + (size_t)NB * 8 + 256;
    if (ws_size < need) {
        sg4d_direct<<<(n + 255) / 256, 256, 0, stream>>>(uvwq, grid, out, n);
        return;
    }

    char* w = (char*)d_ws;
    v4f* s_uvwq = (v4f*)w;
    int* s_idx  = (int*)(w + (size_t)n * 16);
    int* hist   = (int*)(w + (size_t)n * 20);
    int* cursor = hist + NB;

    int pblocks = (n + PBLK - 1) / PBLK;
    hipMemsetAsync(hist, 0, NB * sizeof(int), stream);
    k_hist<<<pblocks, PT, 0, stream>>>(uvwq, hist, n);
    k_scan<<<1, NB, 0, stream>>>(hist, cursor);
    k_part<<<pblocks, PT, 0, stream>>>(uvwq, cursor, s_uvwq, s_idx, n);
    k_interp<<<(n + 255) / 256, 256, 0, stream>>>(s_uvwq, s_idx, grid, out, n);
}

// Round 8
// 650.775 us; speedup vs baseline: 1.8503x; 1.0003x over previous
//
#include <hip/hip_runtime.h>

// SpatialGrid4D: quadrilinear interp of (32,32,32,32,8) f32 grid at N=4.19M
// random points. Round-7 post-mortem: interp is bound by per-lane VMEM
// address cost of divergent gathers (36 lane-addrs/point), not cache misses
// (FETCH=67MB) nor VALU (6%). Round 8: fp16 grid (halves corner loads 32->16
// and bytes 512->256/pt), packed uint4 point record (coords 4x26b + idx 22b,
// kills the s_idx stream), full f16 pk-fma lerp tree.

typedef float  v4f __attribute__((ext_vector_type(4)));
typedef float  v8f __attribute__((ext_vector_type(8)));
typedef _Float16 h8 __attribute__((ext_vector_type(8)));

#define NB   256    // buckets: key = (iq<<3) | (iw>>2)
#define PBLK 2048   // points per partition block
#define PT   256    // threads per partition block
#define Q26  67108864.0f            // 2^26
#define S31  (31.0f / 67108864.0f)  // 31 * 2^-26

__device__ __forceinline__ uint qz(float x) {           // floor(x * 2^26), exact
    uint u = (uint)(x * Q26);
    return u > 0x3FFFFFFu ? 0x3FFFFFFu : u;
}
__device__ __forceinline__ int key_from_q(uint wx, uint qx) {
    int iw = (int)((float)wx * S31);
    int iq = (int)((float)qx * S31);
    return (iq << 3) | (iw >> 2);
}

__global__ __launch_bounds__(256) void k_cvt(const v4f* __restrict__ gf,
                                             h8* __restrict__ gh, int nitems) {
    int i = blockIdx.x * 256 + threadIdx.x;
    if (i >= nitems) return;
    v4f a = gf[2 * i], b = gf[2 * i + 1];
    h8 h = {(_Float16)a.x, (_Float16)a.y, (_Float16)a.z, (_Float16)a.w,
            (_Float16)b.x, (_Float16)b.y, (_Float16)b.z, (_Float16)b.w};
    gh[i] = h;
}

__global__ __launch_bounds__(PT) void k_hist(const v4f* __restrict__ uvwq,
                                             int* __restrict__ hist, int n) {
    __shared__ int lh[NB];
    int t = threadIdx.x;
    lh[t] = 0;
    __syncthreads();
    int base = blockIdx.x * PBLK;
#pragma unroll
    for (int j = 0; j < 8; ++j) {
        int i = base + j * PT + t;
        if (i < n) {
            v4f p = uvwq[i];
            atomicAdd(&lh[key_from_q(qz(p.z), qz(p.w))], 1);
        }
    }
    __syncthreads();
    atomicAdd(&hist[t], lh[t]);
}

__global__ __launch_bounds__(NB) void k_scan(const int* __restrict__ hist,
                                             int* __restrict__ cursor) {
    __shared__ int sh[NB];
    int t = threadIdx.x;
    int v = hist[t];
    sh[t] = v;
    __syncthreads();
    for (int off = 1; off < NB; off <<= 1) {
        int x = (t >= off) ? sh[t - off] : 0;
        __syncthreads();
        sh[t] += x;
        __syncthreads();
    }
    cursor[t] = sh[t] - v;   // exclusive
}

// Partition: bin 2048 points into LDS by bucket, reserve per-bucket global
// ranges (1 atomic/bucket/block), burst-write packed uint4 records.
__global__ __launch_bounds__(PT) void k_part(const v4f* __restrict__ uvwq,
                                             int* __restrict__ cursor,
                                             uint4* __restrict__ s_rec, int n) {
    __shared__ int lh[NB], lbase[NB], lrsv[NB], lcnt[NB];
    __shared__ uint4 sv[PBLK];
    int t = threadIdx.x;
    int base = blockIdx.x * PBLK;

    lh[t] = 0;
    lcnt[t] = 0;
    __syncthreads();

    uint4 rec[8];
    int key[8];
#pragma unroll
    for (int j = 0; j < 8; ++j) {
        int i = base + j * PT + t;
        if (i < n) {
            v4f p = uvwq[i];
            uint ux = qz(p.x), vx = qz(p.y), wx = qz(p.z), qx = qz(p.w);
            uint idx = (uint)i;
            rec[j].x = ux | ((idx & 63u) << 26);
            rec[j].y = vx | (((idx >> 6) & 63u) << 26);
            rec[j].z = wx | (((idx >> 12) & 63u) << 26);
            rec[j].w = qx | (((idx >> 18) & 63u) << 26);
            key[j] = key_from_q(wx, qx);
            atomicAdd(&lh[key[j]], 1);
        } else key[j] = -1;
    }
    __syncthreads();

    // exclusive scan of lh into lbase
    int v = lh[t];
    lbase[t] = v;
    __syncthreads();
    for (int off = 1; off < NB; off <<= 1) {
        int x = (t >= off) ? lbase[t - off] : 0;
        __syncthreads();
        lbase[t] += x;
        __syncthreads();
    }
    int excl = lbase[t] - v;
    __syncthreads();
    lbase[t] = excl;
    lrsv[t] = atomicAdd(&cursor[t], v);
    __syncthreads();

    // LDS reorder (bucket-grouped within block)
#pragma unroll
    for (int j = 0; j < 8; ++j) {
        if (key[j] >= 0) {
            int r = lbase[key[j]] + atomicAdd(&lcnt[key[j]], 1);
            sv[r] = rec[j];
        }
    }
    __syncthreads();

    // burst write: consecutive LDS slots -> consecutive global addrs per bucket
    int cnt = min(PBLK, n - base);
#pragma unroll
    for (int j = 0; j < 8; ++j) {
        int s = j * PT + t;
        if (s < cnt) {
            uint4 q = sv[s];
            int k = key_from_q(q.z & 0x3FFFFFFu, q.w & 0x3FFFFFFu);
            s_rec[lrsv[k] + (s - lbase[k])] = q;
        }
    }
}

__device__ __forceinline__ h8 splat8(_Float16 x) {
    h8 r = {x, x, x, x, x, x, x, x};
    return r;
}
__device__ __forceinline__ h8 lerp8(h8 x0, h8 x1, h8 t) {
    return x0 + t * (x1 - x0);   // -> v_pk_fma_f16 (ffp-contract)
}

// Interp over sorted packed records; fp16 grid; XCD-chunked swizzle.
__global__ __launch_bounds__(256) void k_interp(const uint4* __restrict__ s_rec,
                                                const _Float16* __restrict__ gridh,
                                                v4f* __restrict__ out, int n) {
    int nb = gridDim.x;
    int b = blockIdx.x;
    int swz = (nb & 7) ? b : (b & 7) * (nb >> 3) + (b >> 3);
    int g = swz * 256 + threadIdx.x;
    if (g >= n) return;

    uint4 rec = s_rec[g];
    float fu = (float)(rec.x & 0x3FFFFFFu) * S31;
    float fv = (float)(rec.y & 0x3FFFFFFu) * S31;
    float fw = (float)(rec.z & 0x3FFFFFFu) * S31;
    float fq = (float)(rec.w & 0x3FFFFFFu) * S31;
    int oi = (int)((rec.x >> 26) | ((rec.y >> 26) << 6) |
                   ((rec.z >> 26) << 12) | ((rec.w >> 26) << 18));

    int iu = (int)fu, iv = (int)fv, iw = (int)fw, iq = (int)fq;
    h8 a8 = splat8((_Float16)(fu - (float)iu));
    h8 b8 = splat8((_Float16)(fv - (float)iv));
    h8 g8 = splat8((_Float16)(fw - (float)iw));
    h8 d8 = splat8((_Float16)(fq - (float)iq));

    const _Float16* cellh = gridh + (size_t)((((iq * 32 + iw) * 32) + iv) * 32 + iu) * 8;

    h8 xa[8];
#pragma unroll
    for (int k = 0; k < 8; ++k) {
        const int oq = k >> 2, ow = (k >> 1) & 1, ov = k & 1;
        const h8* cp = (const h8*)(cellh + oq * 262144 + ow * 8192 + ov * 256);
        h8 h0 = cp[0];   // corner ou=0, 8 latents
        h8 h1 = cp[1];   // corner ou=1, 8 latents
        xa[k] = lerp8(h0, h1, a8);
    }

    h8 xb[4];
#pragma unroll
    for (int k = 0; k < 4; ++k) xb[k] = lerp8(xa[2 * k], xa[2 * k + 1], b8);
    h8 xg[2];
#pragma unroll
    for (int k = 0; k < 2; ++k) xg[k] = lerp8(xb[2 * k], xb[2 * k + 1], g8);
    h8 xd = lerp8(xg[0], xg[1], d8);

    v8f rf = __builtin_convertvector(xd, v8f);
    v4f o0 = __builtin_shufflevector(rf, rf, 0, 1, 2, 3);
    v4f o1 = __builtin_shufflevector(rf, rf, 4, 5, 6, 7);
    __builtin_nontemporal_store(o0, &out[2 * oi + 0]);
    __builtin_nontemporal_store(o1, &out[2 * oi + 1]);
}

// ---------------- fallback: direct f32 ----------------
__global__ __launch_bounds__(256) void sg4d_direct(const v4f* __restrict__ uvwq,
                                                   const float* __restrict__ grid,
                                                   v4f* __restrict__ out, int n) {
    int i = blockIdx.x * 256 + threadIdx.x;
    if (i >= n) return;
    v4f p = uvwq[i];
    float fu = p.x * 31.0f, fv = p.y * 31.0f, fw = p.z * 31.0f, fq = p.w * 31.0f;
    int iu = (int)fu, iv = (int)fv, iw = (int)fw, iq = (int)fq;
    float a = fu - (float)iu, b = fv - (float)iv, g = fw - (float)iw, d = fq - (float)iq;
    const float* base = grid + ((((iq * 32 + iw) * 32) + iv) * 32 + iu) * 8;
    float xa[8][8];
#pragma unroll
    for (int k = 0; k < 8; ++k) {
        const int oq = k >> 2, ow = (k >> 1) & 1, ov = k & 1;
        const v4f* c = (const v4f*)(base + oq * 262144 + ow * 8192 + ov * 256);
        v4f c0 = c[0], c1 = c[1], c2 = c[2], c3 = c[3];
        xa[k][0] = fmaf(a, c2.x - c0.x, c0.x);
        xa[k][1] = fmaf(a, c2.y - c0.y, c0.y);
        xa[k][2] = fmaf(a, c2.z - c0.z, c0.z);
        xa[k][3] = fmaf(a, c2.w - c0.w, c0.w);
        xa[k][4] = fmaf(a, c3.x - c1.x, c1.x);
        xa[k][5] = fmaf(a, c3.y - c1.y, c1.y);
        xa[k][6] = fmaf(a, c3.z - c1.z, c1.z);
        xa[k][7] = fmaf(a, c3.w - c1.w, c1.w);
    }
    float xb[4][8];
#pragma unroll
    for (int k = 0; k < 4; ++k)
#pragma unroll
        for (int j = 0; j < 8; ++j)
            xb[k][j] = fmaf(b, xa[2 * k + 1][j] - xa[2 * k][j], xa[2 * k][j]);
    float xg[2][8];
#pragma unroll
    for (int k = 0; k < 2; ++k)
#pragma unroll
        for (int j = 0; j < 8; ++j)
            xg[k][j] = fmaf(g, xb[2 * k + 1][j] - xb[2 * k][j], xb[2 * k][j]);
    float r[8];
#pragma unroll
    for (int j = 0; j < 8; ++j)
        r[j] = fmaf(d, xg[1][j] - xg[0][j], xg[0][j]);
    v4f o0 = { r[0], r[1], r[2], r[3] };
    v4f o1 = { r[4], r[5], r[6], r[7] };
    __builtin_nontemporal_store(o0, &out[2 * i + 0]);
    __builtin_nontemporal_store(o1, &out[2 * i + 1]);
}

extern "C" void kernel_launch(void* const* d_in, const int* in_sizes, int n_in,
                              void* d_out, int out_size, void* d_ws, size_t ws_size,
                              hipStream_t stream) {
    const v4f*   uvwq = (const v4f*)d_in[0];
    const float* grid = (const float*)d_in[1];
    v4f*         out  = (v4f*)d_out;
    int n  = in_sizes[0] / 4;
    int ge = in_sizes[1];                   // grid elements (8.39M)

    size_t need = (size_t)n * 16 + (size_t)ge * 2 + NB * 8 + 256;
    if (ws_size < need) {
        sg4d_direct<<<(n + 255) / 256, 256, 0, stream>>>(uvwq, grid, out, n);
        return;
    }

    char* w = (char*)d_ws;
    uint4*     s_rec = (uint4*)w;
    _Float16*  gridh = (_Float16*)(w + (size_t)n * 16);
    int*       hist  = (int*)(w + (size_t)n * 16 + (size_t)ge * 2);
    int*       cursor = hist + NB;

    int pblocks = (n + PBLK - 1) / PBLK;
    int citems = ge / 8;
    hipMemsetAsync(hist, 0, NB * sizeof(int), stream);
    k_cvt <<<(citems + 255) / 256, 256, 0, stream>>>((const v4f*)grid, (h8*)gridh, citems);
    k_hist<<<pblocks, PT, 0, stream>>>(uvwq, hist, n);
    k_scan<<<1, NB, 0, stream>>>(hist, cursor);
    k_part<<<pblocks, PT, 0, stream>>>(uvwq, cursor, s_rec, n);
    k_interp<<<(n + 255) / 256, 256, 0, stream>>>(s_rec, gridh, out, n);
}